// Round 1
// baseline (993.611 us; speedup 1.0000x reference)
//
#include <hip/hip_runtime.h>
#include <stdint.h>

#define NPTS 8192
#define CDIM 128
#define KNNK 16
#define WPAD 136
#define WELEM (CDIM*WPAD)          // 17408 elems per transposed weight image
#define SCALE 0.08838834764831845f
#define LDS_BYTES 152576

typedef __attribute__((ext_vector_type(4))) float f32x4;
typedef __attribute__((ext_vector_type(8))) short s16x8;

__device__ __forceinline__ unsigned short to_bf16(float f){
  union { float f; unsigned int u; } v; v.f = f;
  return (unsigned short)((v.u + 0x7fffu + ((v.u >> 16) & 1u)) >> 16);
}

__device__ __forceinline__ s16x8 cvt8(const float* p){
  float4 lo = *(const float4*)p;
  float4 hi = *(const float4*)(p + 4);
  s16x8 f;
  f[0]=(short)to_bf16(lo.x); f[1]=(short)to_bf16(lo.y);
  f[2]=(short)to_bf16(lo.z); f[3]=(short)to_bf16(lo.w);
  f[4]=(short)to_bf16(hi.x); f[5]=(short)to_bf16(hi.y);
  f[6]=(short)to_bf16(hi.z); f[7]=(short)to_bf16(hi.w);
  return f;
}

// ---------------- prep: transpose weights to bf16 images in ws, compute p2 ----------------
__global__ __launch_bounds__(256) void prep_kernel(
    const float* __restrict__ Wq, const float* __restrict__ Wk,
    const float* __restrict__ Wv, const float* __restrict__ Wp2,
    const float* __restrict__ Wg1, const float* __restrict__ Wg2,
    const float* __restrict__ pos,
    unsigned short* __restrict__ wt, float* __restrict__ p2out)
{
  int t = blockIdx.x*256 + threadIdx.x;
  if (t < 6*WELEM){
    int w = t / WELEM, rem = t % WELEM, c = rem / WPAD, i = rem % WPAD;
    const float* src = (w==0)?Wq:(w==1)?Wk:(w==2)?Wv:(w==3)?Wp2:(w==4)?Wg1:Wg2;
    float v = (i < CDIM) ? src[i*CDIM + c] : 0.0f;
    if (w == 1) v = -v;                     // store -Wk so k folds into the t accumulator
    wt[t] = to_bf16(v);
  } else {
    int m = t - 6*WELEM;
    if (m < 2*NPTS){
      float xx = pos[m*3+0], yy = pos[m*3+1], zz = pos[m*3+2];
      p2out[m] = __fadd_rn(__fadd_rn(__fmul_rn(xx,xx), __fmul_rn(yy,yy)), __fmul_rn(zz,zz));
    }
  }
}

// ---------------- kNN: one wave per query, exact top-16 by (d2, idx) ----------------
__global__ __launch_bounds__(256) void knn_kernel(
    const float* __restrict__ pos, const float* __restrict__ p2,
    int* __restrict__ idxout)
{
  const int lane = threadIdx.x & 63;
  const int g = blockIdx.x*4 + (threadIdx.x >> 6);
  const int b = g >> 13, n = g & (NPTS-1);
  const float* posb = pos + (size_t)b*NPTS*3;
  const float* p2b  = p2  + (size_t)b*NPTS;
  const float qx = posb[n*3], qy = posb[n*3+1], qz = posb[n*3+2];
  const float q2 = p2b[n];

  float bd[16]; int bi[16];
#pragma unroll
  for (int jj = 0; jj < 16; ++jj){
    int m = jj*64 + lane;
    float cx = posb[m*3], cy = posb[m*3+1], cz = posb[m*3+2];
    float dot = __builtin_fmaf(cz, qz, __builtin_fmaf(cy, qy, __fmul_rn(cx,qx)));
    float d  = __fsub_rn(__fadd_rn(q2, p2b[m]), __fadd_rn(dot,dot));
    bd[jj] = d; bi[jj] = m;
  }
  float wd = bd[0]; int wi = bi[0];
#pragma unroll
  for (int e = 1; e < 16; ++e){
    bool gt = (bd[e] > wd) || (bd[e] == wd && bi[e] > wi);
    if (gt){ wd = bd[e]; wi = bi[e]; }
  }
  for (int jj = 16; jj < 128; ++jj){
    int m = jj*64 + lane;
    float cx = posb[m*3], cy = posb[m*3+1], cz = posb[m*3+2];
    float dot = __builtin_fmaf(cz, qz, __builtin_fmaf(cy, qy, __fmul_rn(cx,qx)));
    float d  = __fsub_rn(__fadd_rn(q2, p2b[m]), __fadd_rn(dot,dot));
    bool ins = (d < wd) || (d == wd && m < wi);
    if (ins){
      bool done = false;
#pragma unroll
      for (int e = 0; e < 16; ++e){
        bool h = (!done) && (bd[e] == wd) && (bi[e] == wi);
        if (h){ bd[e] = d; bi[e] = m; done = true; }
      }
      wd = bd[0]; wi = bi[0];
#pragma unroll
      for (int e = 1; e < 16; ++e){
        bool gt2 = (bd[e] > wd) || (bd[e] == wd && bi[e] > wi);
        if (gt2){ wd = bd[e]; wi = bi[e]; }
      }
    }
  }
  // 16-round cross-wave extraction of lex-min (d, idx)
  for (int t = 0; t < 16; ++t){
    float ld = bd[0]; int li = bi[0];
#pragma unroll
    for (int e = 1; e < 16; ++e){
      bool lt = (bd[e] < ld) || (bd[e] == ld && bi[e] < li);
      if (lt){ ld = bd[e]; li = bi[e]; }
    }
#pragma unroll
    for (int off = 1; off < 64; off <<= 1){
      float od = __shfl_xor(ld, off);
      int   oi = __shfl_xor(li, off);
      bool lt = (od < ld) || (od == ld && oi < li);
      if (lt){ ld = od; li = oi; }
    }
    if (lane == 0) idxout[(size_t)g*KNNK + t] = li;
#pragma unroll
    for (int e = 0; e < 16; ++e){
      if (bd[e] == ld && bi[e] == li){ bd[e] = __builtin_inff(); bi[e] = 0x7fffffff; }
    }
  }
}

// ---------------- fused transform: 4 waves x 4 points, MFMA bf16 ----------------
__global__ __launch_bounds__(256, 1) void fused_kernel(
    const float* __restrict__ x, const float* __restrict__ pos,
    const float* __restrict__ bq, const float* __restrict__ bk,
    const float* __restrict__ bv, const float* __restrict__ Wp1,
    const float* __restrict__ bp1, const float* __restrict__ bp2,
    const float* __restrict__ bg1, const float* __restrict__ bg2,
    const int* __restrict__ idxws, const unsigned short* __restrict__ wt,
    float* __restrict__ out)
{
  extern __shared__ char smem[];
  unsigned short* WTl = (unsigned short*)smem;               // 3 slots x WELEM bf16
  float* q_lds = (float*)(smem + 104448);                    // [16][128] f32
  unsigned short* t_base = (unsigned short*)(smem + 112640); // per-wave [2][16][136] bf16
  float* blds = (float*)(smem + 147456);                     // 1280 f32: bq bk bv bp2 bg1 bg2 bp1 Wp1(3x128)

  const int tid = threadIdx.x;
  const int lane = tid & 63, w = tid >> 6;
  const int r = lane & 15, grp = lane >> 4;
  const int pbase = blockIdx.x * 16;
  const int b = pbase >> 13;

  // stage biases + Wp1 (f32)
  for (int e = tid; e < 1280; e += 256){
    float v;
    if      (e < 128)  v = bq[e];
    else if (e < 256)  v = bk[e-128];
    else if (e < 384)  v = bv[e-256];
    else if (e < 512)  v = bp2[e-384];
    else if (e < 640)  v = bg1[e-512];
    else if (e < 768)  v = bg2[e-640];
    else if (e < 896)  v = bp1[e-768];
    else               v = Wp1[e-896];
    blds[e] = v;
  }
  // stage Wq, -Wk, Wv (pre-transposed bf16 images, linear copy)
  {
    const float4* s = (const float4*)wt;
    float4* d = (float4*)smem;
    for (int cix = tid; cix < 3*WELEM/8; cix += 256) d[cix] = s[cix];
  }
  // per-lane neighbor info for this wave's 4 points (lane's row r = neighbor slot)
  int nbr[4]; float relx[4], rely[4], relz[4];
#pragma unroll
  for (int j = 0; j < 4; ++j){
    int gp = pbase + w*4 + j;
    nbr[j] = idxws[(size_t)gp*KNNK + r];
    const float* pq = pos + (size_t)gp*3;
    const float* pn = pos + ((size_t)b*NPTS + nbr[j])*3;
    relx[j] = pq[0]-pn[0]; rely[j] = pq[1]-pn[1]; relz[j] = pq[2]-pn[2];
  }
  // A-frags of x rows for the q tile (16 points of the block)
  s16x8 qa[4];
  {
    const float* xr = x + (size_t)(pbase + r)*CDIM;
#pragma unroll
    for (int kk = 0; kk < 4; ++kk) qa[kk] = cvt8(xr + kk*32 + grp*8);
  }
  __syncthreads();   // staging visible

  auto ldB = [&](int slot, int ct, int kk) -> s16x8 {
    return *(const s16x8*)&WTl[slot*WELEM + (ct*16 + r)*WPAD + kk*32 + grp*8];
  };

  // ---- q = x@Wq + bq, distributed: wave w computes column tiles 2w, 2w+1 ----
  {
    f32x4 qacc[2] = { {0.f,0.f,0.f,0.f}, {0.f,0.f,0.f,0.f} };
#pragma unroll
    for (int c2 = 0; c2 < 2; ++c2){
      int ct = w*2 + c2;
#pragma unroll
      for (int kk = 0; kk < 4; ++kk)
        qacc[c2] = __builtin_amdgcn_mfma_f32_16x16x32_bf16(qa[kk], ldB(0,ct,kk), qacc[c2], 0,0,0);
    }
#pragma unroll
    for (int c2 = 0; c2 < 2; ++c2){
      int col = (w*2+c2)*16 + r;
#pragma unroll
      for (int jj = 0; jj < 4; ++jj)
        q_lds[(grp*4+jj)*CDIM + col] = qacc[c2][jj] + blds[col];
    }
  }
  // ---- pe1 = relu(rel@Wp1 + bp1) directly in A-frag layout ----
  s16x8 pf[4][4];
#pragma unroll
  for (int j = 0; j < 4; ++j)
#pragma unroll
    for (int kk = 0; kk < 4; ++kk){
      s16x8 f;
#pragma unroll
      for (int i = 0; i < 8; ++i){
        int kc = kk*32 + grp*8 + i;
        float s = relx[j]*blds[896+kc] + rely[j]*blds[1024+kc] + relz[j]*blds[1152+kc] + blds[768+kc];
        f[i] = (short)to_bf16(fmaxf(s, 0.f));
      }
      pf[j][kk] = f;
    }
  __syncthreads();   // Wq fully consumed, q_lds written

  // ---- stage Wp2 -> slot0 ----
  {
    const float4* s = (const float4*)(wt + 3*WELEM);
    float4* d = (float4*)smem;
    for (int cix = tid; cix < WELEM/8; cix += 256) d[cix] = s[cix];
  }
  __syncthreads();

  // ---- at = pe1@Wp2 ; av = copy ; at += nb@(-Wk) ; av += nb@Wv ----
  f32x4 at[4][8], av[4][8];
#pragma unroll
  for (int j=0;j<4;++j)
#pragma unroll
    for (int ct=0;ct<8;++ct) at[j][ct] = (f32x4){0.f,0.f,0.f,0.f};
#pragma unroll
  for (int ct=0;ct<8;++ct)
#pragma unroll
    for (int kk=0;kk<4;++kk){
      s16x8 bw = ldB(0,ct,kk);
#pragma unroll
      for (int j=0;j<4;++j)
        at[j][ct] = __builtin_amdgcn_mfma_f32_16x16x32_bf16(pf[j][kk], bw, at[j][ct], 0,0,0);
    }
#pragma unroll
  for (int j=0;j<4;++j)
#pragma unroll
    for (int ct=0;ct<8;++ct) av[j][ct] = at[j][ct];
#pragma unroll
  for (int kk=0;kk<4;++kk){
    s16x8 nf[4];
#pragma unroll
    for (int j=0;j<4;++j)
      nf[j] = cvt8(x + ((size_t)b*NPTS + nbr[j])*CDIM + kk*32 + grp*8);
#pragma unroll
    for (int ct=0;ct<8;++ct){
      s16x8 wk = ldB(1,ct,kk);
      s16x8 wv = ldB(2,ct,kk);
#pragma unroll
      for (int j=0;j<4;++j) at[j][ct] = __builtin_amdgcn_mfma_f32_16x16x32_bf16(nf[j], wk, at[j][ct], 0,0,0);
#pragma unroll
      for (int j=0;j<4;++j) av[j][ct] = __builtin_amdgcn_mfma_f32_16x16x32_bf16(nf[j], wv, av[j][ct], 0,0,0);
    }
  }
  // t = (q - k + pe) * scale   (at already holds pe - (nb@Wk); add q + bp2 - bk)
#pragma unroll
  for (int j=0;j<4;++j){
    int prow = (w*4+j)*CDIM;
#pragma unroll
    for (int ct=0;ct<8;++ct){
      int col = ct*16+r;
      float add = q_lds[prow+col] + blds[384+col] - blds[128+col];
#pragma unroll
      for (int jj=0;jj<4;++jj) at[j][ct][jj] = (at[j][ct][jj] + add)*SCALE;
    }
  }
  __syncthreads();   // Wp2/-Wk/Wv fully consumed

  // ---- stage Wg1 -> slot0, Wg2 -> slot1 ----
  {
    const float4* s = (const float4*)(wt + 4*WELEM);
    float4* d = (float4*)smem;
    for (int cix = tid; cix < 2*WELEM/8; cix += 256) d[cix] = s[cix];
  }
  __syncthreads();

  // ---- gating MLP + softmax + output, 2 points per round ----
  unsigned short* tl = t_base + w*(2*16*WPAD);
#pragma unroll
  for (int pr=0; pr<2; ++pr){
    if (pr) __syncthreads();
#pragma unroll
    for (int jh=0; jh<2; ++jh){
      int j = pr*2+jh;
#pragma unroll
      for (int ct=0;ct<8;++ct)
#pragma unroll
        for (int jj=0;jj<4;++jj)
          tl[(jh*16 + grp*4+jj)*WPAD + ct*16 + r] = to_bf16(at[j][ct][jj]);
    }
    __syncthreads();
    s16x8 tf[2][4];
#pragma unroll
    for (int jh=0;jh<2;++jh)
#pragma unroll
      for (int kk=0;kk<4;++kk)
        tf[jh][kk] = *(const s16x8*)&tl[(jh*16 + r)*WPAD + kk*32 + grp*8];
    f32x4 hacc[2][8];
#pragma unroll
    for (int jh=0;jh<2;++jh)
#pragma unroll
      for (int ct=0;ct<8;++ct) hacc[jh][ct] = (f32x4){0.f,0.f,0.f,0.f};
#pragma unroll
    for (int ct=0;ct<8;++ct)
#pragma unroll
      for (int kk=0;kk<4;++kk){
        s16x8 bw = ldB(0,ct,kk);
#pragma unroll
        for (int jh=0;jh<2;++jh)
          hacc[jh][ct] = __builtin_amdgcn_mfma_f32_16x16x32_bf16(tf[jh][kk], bw, hacc[jh][ct], 0,0,0);
      }
    __syncthreads();
#pragma unroll
    for (int jh=0;jh<2;++jh)
#pragma unroll
      for (int ct=0;ct<8;++ct){
        int col = ct*16+r; float bb = blds[512+col];
#pragma unroll
        for (int jj=0;jj<4;++jj)
          tl[(jh*16+grp*4+jj)*WPAD + ct*16 + r] = to_bf16(fmaxf(hacc[jh][ct][jj]+bb, 0.f));
      }
    __syncthreads();
    s16x8 hf[2][4];
#pragma unroll
    for (int jh=0;jh<2;++jh)
#pragma unroll
      for (int kk=0;kk<4;++kk)
        hf[jh][kk] = *(const s16x8*)&tl[(jh*16 + r)*WPAD + kk*32 + grp*8];
    f32x4 gacc[2][8];
#pragma unroll
    for (int jh=0;jh<2;++jh)
#pragma unroll
      for (int ct=0;ct<8;++ct) gacc[jh][ct] = (f32x4){0.f,0.f,0.f,0.f};
#pragma unroll
    for (int ct=0;ct<8;++ct)
#pragma unroll
      for (int kk=0;kk<4;++kk){
        s16x8 bw = ldB(1,ct,kk);
#pragma unroll
        for (int jh=0;jh<2;++jh)
          gacc[jh][ct] = __builtin_amdgcn_mfma_f32_16x16x32_bf16(hf[jh][kk], bw, gacc[jh][ct], 0,0,0);
      }
    // softmax over the 16 neighbor rows per column + weighted sum of (v+pe)
#pragma unroll
    for (int jh=0;jh<2;++jh){
      int j = pr*2+jh;
#pragma unroll
      for (int ct=0;ct<8;++ct){
        int col = ct*16+r;
        float gb = blds[640+col];
        float g0v = gacc[jh][ct][0]+gb, g1v = gacc[jh][ct][1]+gb;
        float g2v = gacc[jh][ct][2]+gb, g3v = gacc[jh][ct][3]+gb;
        float mx = fmaxf(fmaxf(g0v,g1v), fmaxf(g2v,g3v));
        mx = fmaxf(mx, __shfl_xor(mx,16));
        mx = fmaxf(mx, __shfl_xor(mx,32));
        float e0=__expf(g0v-mx), e1=__expf(g1v-mx), e2=__expf(g2v-mx), e3=__expf(g3v-mx);
        float vb = blds[256+col] + blds[384+col];     // bv + bp2
        float ss = e0+e1+e2+e3;
        float oo = e0*(av[j][ct][0]+vb) + e1*(av[j][ct][1]+vb)
                 + e2*(av[j][ct][2]+vb) + e3*(av[j][ct][3]+vb);
        ss += __shfl_xor(ss,16); ss += __shfl_xor(ss,32);
        oo += __shfl_xor(oo,16); oo += __shfl_xor(oo,32);
        if (grp == 0) out[(size_t)(pbase + w*4 + j)*CDIM + col] = oo/ss;
      }
    }
  }
}

extern "C" void kernel_launch(void* const* d_in, const int* in_sizes, int n_in,
                              void* d_out, int out_size, void* d_ws, size_t ws_size,
                              hipStream_t stream)
{
  const float* x    = (const float*)d_in[0];
  const float* pos  = (const float*)d_in[1];
  const float* Wq   = (const float*)d_in[2];
  const float* bq   = (const float*)d_in[3];
  const float* Wk   = (const float*)d_in[4];
  const float* bk   = (const float*)d_in[5];
  const float* Wv   = (const float*)d_in[6];
  const float* bv   = (const float*)d_in[7];
  const float* Wp1  = (const float*)d_in[8];
  const float* bp1  = (const float*)d_in[9];
  const float* Wp2  = (const float*)d_in[10];
  const float* bp2  = (const float*)d_in[11];
  const float* Wg1  = (const float*)d_in[12];
  const float* bg1  = (const float*)d_in[13];
  const float* Wg2  = (const float*)d_in[14];
  const float* bg2  = (const float*)d_in[15];
  float* out = (float*)d_out;

  char* ws = (char*)d_ws;
  int*            idxs = (int*)ws;                        // 16384*16*4 = 1048576 B
  unsigned short* wt   = (unsigned short*)(ws + 1048576); // 6*17408*2 = 208896 B
  float*          p2   = (float*)(ws + 1257472);          // 16384*4   = 65536 B

  hipFuncSetAttribute((const void*)fused_kernel,
                      hipFuncAttributeMaxDynamicSharedMemorySize, LDS_BYTES);

  prep_kernel<<<472, 256, 0, stream>>>(Wq, Wk, Wv, Wp2, Wg1, Wg2, pos, wt, p2);
  knn_kernel<<<4096, 256, 0, stream>>>(pos, p2, idxs);
  fused_kernel<<<1024, 256, LDS_BYTES, stream>>>(x, pos, bq, bk, bv, Wp1, bp1, bp2,
                                                 bg1, bg2, idxs, wt, out);
}

// Round 2
// 322.142 us; speedup vs baseline: 3.0844x; 3.0844x over previous
//
#include <hip/hip_runtime.h>
#include <stdint.h>

#define NPTS 8192
#define CDIM 128
#define KNNK 16
#define WPAD 136
#define WELEM (CDIM*WPAD)          // 17408 elems per transposed weight image
#define SCALE 0.08838834764831845f
#define LDS_BYTES 152576

typedef __attribute__((ext_vector_type(4))) float f32x4;
typedef __attribute__((ext_vector_type(8))) short s16x8;

__device__ __forceinline__ unsigned short to_bf16(float f){
  union { float f; unsigned int u; } v; v.f = f;
  return (unsigned short)((v.u + 0x7fffu + ((v.u >> 16) & 1u)) >> 16);
}

__device__ __forceinline__ s16x8 cvt8(const float* p){
  float4 lo = *(const float4*)p;
  float4 hi = *(const float4*)(p + 4);
  s16x8 f;
  f[0]=(short)to_bf16(lo.x); f[1]=(short)to_bf16(lo.y);
  f[2]=(short)to_bf16(lo.z); f[3]=(short)to_bf16(lo.w);
  f[4]=(short)to_bf16(hi.x); f[5]=(short)to_bf16(hi.y);
  f[6]=(short)to_bf16(hi.z); f[7]=(short)to_bf16(hi.w);
  return f;
}

// ---------------- prep: transpose weights to bf16 images in ws, pack pos4 ----------------
__global__ __launch_bounds__(256) void prep_kernel(
    const float* __restrict__ Wq, const float* __restrict__ Wk,
    const float* __restrict__ Wv, const float* __restrict__ Wp2,
    const float* __restrict__ Wg1, const float* __restrict__ Wg2,
    const float* __restrict__ pos,
    unsigned short* __restrict__ wt, float4* __restrict__ pos4)
{
  int t = blockIdx.x*256 + threadIdx.x;
  if (t < 6*WELEM){
    int w = t / WELEM, rem = t % WELEM, c = rem / WPAD, i = rem % WPAD;
    const float* src = (w==0)?Wq:(w==1)?Wk:(w==2)?Wv:(w==3)?Wp2:(w==4)?Wg1:Wg2;
    float v = (i < CDIM) ? src[i*CDIM + c] : 0.0f;
    if (w == 1) v = -v;                     // store -Wk so k folds into the t accumulator
    wt[t] = to_bf16(v);
  } else {
    int m = t - 6*WELEM;
    if (m < 2*NPTS){
      float xx = pos[m*3+0], yy = pos[m*3+1], zz = pos[m*3+2];
      float p2 = __fadd_rn(__fadd_rn(__fmul_rn(xx,xx), __fmul_rn(yy,yy)), __fmul_rn(zz,zz));
      pos4[m] = make_float4(xx, yy, zz, p2);
    }
  }
}

// ---------------- kNN: one wave per query, wave-distributed sorted top-16 ----------------
// Lanes 0..15 hold the current best-16 sorted ascending by lex (d2, idx); state is
// 2 VGPRs/lane -> no scratch. Candidates are filtered against the wave-uniform 16th
// distance (SGPR via readlane); qualifying ones insert via a shfl_up shift step.
__global__ __launch_bounds__(256) void knn_kernel(
    const float4* __restrict__ pos4, int* __restrict__ idxout)
{
  const int lane = threadIdx.x & 63;
  const int g = blockIdx.x*4 + (threadIdx.x >> 6);
  const int b = g >> 13, n = g & (NPTS-1);
  const float4* pb = pos4 + (size_t)b*NPTS;
  const float4 q = pb[n];

  float ld = __builtin_inff(); int li = 0x7fffffff;   // distributed sorted list
  float Td = __builtin_inff(); int Ti = 0x7fffffff;   // wave-uniform worst-of-16

  for (int jj = 0; jj < 128; ++jj){
    const int m = jj*64 + lane;
    float4 c = pb[m];
    float dot = __builtin_fmaf(c.z, q.z, __builtin_fmaf(c.y, q.y, __fmul_rn(c.x, q.x)));
    float d   = __fsub_rn(__fadd_rn(q.w, c.w), __fadd_rn(dot, dot));
    bool ins = (d < Td) || (d == Td && m < Ti);
    unsigned long long mask = __ballot(ins);
    while (mask){
      int s = (int)__builtin_ctzll(mask);
      mask &= mask - 1;
      float bdv = __uint_as_float(__builtin_amdgcn_readlane(__float_as_uint(d), s));
      int   biv = jj*64 + s;
      float pd = __shfl_up(ld, 1);
      int   pi = __shfl_up(li, 1);
      bool gt  = (ld > bdv) || (ld == bdv && li > biv);
      bool pgt = (lane > 0) && ((pd > bdv) || (pd == bdv && pi > biv));
      if (gt){
        if (pgt){ ld = pd; li = pi; }
        else    { ld = bdv; li = biv; }
      }
    }
    Td = __uint_as_float(__builtin_amdgcn_readlane(__float_as_uint(ld), 15));
    Ti = __builtin_amdgcn_readlane(li, 15);
  }
  if (lane < KNNK) idxout[(size_t)g*KNNK + lane] = li;
}

// ---------------- fused transform: 4 waves x 4 points, MFMA bf16 ----------------
__global__ __launch_bounds__(256, 1) void fused_kernel(
    const float* __restrict__ x, const float* __restrict__ pos,
    const float* __restrict__ bq, const float* __restrict__ bk,
    const float* __restrict__ bv, const float* __restrict__ Wp1,
    const float* __restrict__ bp1, const float* __restrict__ bp2,
    const float* __restrict__ bg1, const float* __restrict__ bg2,
    const int* __restrict__ idxws, const unsigned short* __restrict__ wt,
    float* __restrict__ out)
{
  extern __shared__ char smem[];
  unsigned short* WTl = (unsigned short*)smem;               // 3 slots x WELEM bf16
  float* q_lds = (float*)(smem + 104448);                    // [16][128] f32
  unsigned short* t_base = (unsigned short*)(smem + 112640); // per-wave [2][16][136] bf16
  float* blds = (float*)(smem + 147456);                     // 1280 f32: bq bk bv bp2 bg1 bg2 bp1 Wp1(3x128)

  const int tid = threadIdx.x;
  const int lane = tid & 63, w = tid >> 6;
  const int r = lane & 15, grp = lane >> 4;
  const int pbase = blockIdx.x * 16;
  const int b = pbase >> 13;

  // stage biases + Wp1 (f32)
  for (int e = tid; e < 1280; e += 256){
    float v;
    if      (e < 128)  v = bq[e];
    else if (e < 256)  v = bk[e-128];
    else if (e < 384)  v = bv[e-256];
    else if (e < 512)  v = bp2[e-384];
    else if (e < 640)  v = bg1[e-512];
    else if (e < 768)  v = bg2[e-640];
    else if (e < 896)  v = bp1[e-768];
    else               v = Wp1[e-896];
    blds[e] = v;
  }
  // stage Wq, -Wk, Wv (pre-transposed bf16 images, linear copy)
  {
    const float4* s = (const float4*)wt;
    float4* d = (float4*)smem;
    for (int cix = tid; cix < 3*WELEM/8; cix += 256) d[cix] = s[cix];
  }
  // per-lane neighbor info for this wave's 4 points (lane's row r = neighbor slot)
  int nbr[4]; float relx[4], rely[4], relz[4];
#pragma unroll
  for (int j = 0; j < 4; ++j){
    int gp = pbase + w*4 + j;
    nbr[j] = idxws[(size_t)gp*KNNK + r];
    const float* pq = pos + (size_t)gp*3;
    const float* pn = pos + ((size_t)b*NPTS + nbr[j])*3;
    relx[j] = pq[0]-pn[0]; rely[j] = pq[1]-pn[1]; relz[j] = pq[2]-pn[2];
  }
  // A-frags of x rows for the q tile (16 points of the block)
  s16x8 qa[4];
  {
    const float* xr = x + (size_t)(pbase + r)*CDIM;
#pragma unroll
    for (int kk = 0; kk < 4; ++kk) qa[kk] = cvt8(xr + kk*32 + grp*8);
  }
  __syncthreads();   // staging visible

  auto ldB = [&](int slot, int ct, int kk) -> s16x8 {
    return *(const s16x8*)&WTl[slot*WELEM + (ct*16 + r)*WPAD + kk*32 + grp*8];
  };

  // ---- q = x@Wq + bq, distributed: wave w computes column tiles 2w, 2w+1 ----
  {
    f32x4 qacc[2] = { {0.f,0.f,0.f,0.f}, {0.f,0.f,0.f,0.f} };
#pragma unroll
    for (int c2 = 0; c2 < 2; ++c2){
      int ct = w*2 + c2;
#pragma unroll
      for (int kk = 0; kk < 4; ++kk)
        qacc[c2] = __builtin_amdgcn_mfma_f32_16x16x32_bf16(qa[kk], ldB(0,ct,kk), qacc[c2], 0,0,0);
    }
#pragma unroll
    for (int c2 = 0; c2 < 2; ++c2){
      int col = (w*2+c2)*16 + r;
#pragma unroll
      for (int jj = 0; jj < 4; ++jj)
        q_lds[(grp*4+jj)*CDIM + col] = qacc[c2][jj] + blds[col];
    }
  }
  // ---- pe1 = relu(rel@Wp1 + bp1) directly in A-frag layout ----
  s16x8 pf[4][4];
#pragma unroll
  for (int j = 0; j < 4; ++j)
#pragma unroll
    for (int kk = 0; kk < 4; ++kk){
      s16x8 f;
#pragma unroll
      for (int i = 0; i < 8; ++i){
        int kc = kk*32 + grp*8 + i;
        float s = relx[j]*blds[896+kc] + rely[j]*blds[1024+kc] + relz[j]*blds[1152+kc] + blds[768+kc];
        f[i] = (short)to_bf16(fmaxf(s, 0.f));
      }
      pf[j][kk] = f;
    }
  __syncthreads();   // Wq fully consumed, q_lds written

  // ---- stage Wp2 -> slot0 ----
  {
    const float4* s = (const float4*)(wt + 3*WELEM);
    float4* d = (float4*)smem;
    for (int cix = tid; cix < WELEM/8; cix += 256) d[cix] = s[cix];
  }
  __syncthreads();

  // ---- at = pe1@Wp2 ; av = copy ; at += nb@(-Wk) ; av += nb@Wv ----
  f32x4 at[4][8], av[4][8];
#pragma unroll
  for (int j=0;j<4;++j)
#pragma unroll
    for (int ct=0;ct<8;++ct) at[j][ct] = (f32x4){0.f,0.f,0.f,0.f};
#pragma unroll
  for (int ct=0;ct<8;++ct)
#pragma unroll
    for (int kk=0;kk<4;++kk){
      s16x8 bw = ldB(0,ct,kk);
#pragma unroll
      for (int j=0;j<4;++j)
        at[j][ct] = __builtin_amdgcn_mfma_f32_16x16x32_bf16(pf[j][kk], bw, at[j][ct], 0,0,0);
    }
#pragma unroll
  for (int j=0;j<4;++j)
#pragma unroll
    for (int ct=0;ct<8;++ct) av[j][ct] = at[j][ct];
#pragma unroll
  for (int kk=0;kk<4;++kk){
    s16x8 nf[4];
#pragma unroll
    for (int j=0;j<4;++j)
      nf[j] = cvt8(x + ((size_t)b*NPTS + nbr[j])*CDIM + kk*32 + grp*8);
#pragma unroll
    for (int ct=0;ct<8;++ct){
      s16x8 wk = ldB(1,ct,kk);
      s16x8 wv = ldB(2,ct,kk);
#pragma unroll
      for (int j=0;j<4;++j) at[j][ct] = __builtin_amdgcn_mfma_f32_16x16x32_bf16(nf[j], wk, at[j][ct], 0,0,0);
#pragma unroll
      for (int j=0;j<4;++j) av[j][ct] = __builtin_amdgcn_mfma_f32_16x16x32_bf16(nf[j], wv, av[j][ct], 0,0,0);
    }
  }
  // t = (q - k + pe) * scale   (at already holds pe - (nb@Wk); add q + bp2 - bk)
#pragma unroll
  for (int j=0;j<4;++j){
    int prow = (w*4+j)*CDIM;
#pragma unroll
    for (int ct=0;ct<8;++ct){
      int col = ct*16+r;
      float add = q_lds[prow+col] + blds[384+col] - blds[128+col];
#pragma unroll
      for (int jj=0;jj<4;++jj) at[j][ct][jj] = (at[j][ct][jj] + add)*SCALE;
    }
  }
  __syncthreads();   // Wp2/-Wk/Wv fully consumed

  // ---- stage Wg1 -> slot0, Wg2 -> slot1 ----
  {
    const float4* s = (const float4*)(wt + 4*WELEM);
    float4* d = (float4*)smem;
    for (int cix = tid; cix < 2*WELEM/8; cix += 256) d[cix] = s[cix];
  }
  __syncthreads();

  // ---- gating MLP + softmax + output, 2 points per round ----
  unsigned short* tl = t_base + w*(2*16*WPAD);
#pragma unroll
  for (int pr=0; pr<2; ++pr){
    if (pr) __syncthreads();
#pragma unroll
    for (int jh=0; jh<2; ++jh){
      int j = pr*2+jh;
#pragma unroll
      for (int ct=0;ct<8;++ct)
#pragma unroll
        for (int jj=0;jj<4;++jj)
          tl[(jh*16 + grp*4+jj)*WPAD + ct*16 + r] = to_bf16(at[j][ct][jj]);
    }
    __syncthreads();
    s16x8 tf[2][4];
#pragma unroll
    for (int jh=0;jh<2;++jh)
#pragma unroll
      for (int kk=0;kk<4;++kk)
        tf[jh][kk] = *(const s16x8*)&tl[(jh*16 + r)*WPAD + kk*32 + grp*8];
    f32x4 hacc[2][8];
#pragma unroll
    for (int jh=0;jh<2;++jh)
#pragma unroll
      for (int ct=0;ct<8;++ct) hacc[jh][ct] = (f32x4){0.f,0.f,0.f,0.f};
#pragma unroll
    for (int ct=0;ct<8;++ct)
#pragma unroll
      for (int kk=0;kk<4;++kk){
        s16x8 bw = ldB(0,ct,kk);
#pragma unroll
        for (int jh=0;jh<2;++jh)
          hacc[jh][ct] = __builtin_amdgcn_mfma_f32_16x16x32_bf16(tf[jh][kk], bw, hacc[jh][ct], 0,0,0);
      }
    __syncthreads();
#pragma unroll
    for (int jh=0;jh<2;++jh)
#pragma unroll
      for (int ct=0;ct<8;++ct){
        int col = ct*16+r; float bb = blds[512+col];
#pragma unroll
        for (int jj=0;jj<4;++jj)
          tl[(jh*16+grp*4+jj)*WPAD + ct*16 + r] = to_bf16(fmaxf(hacc[jh][ct][jj]+bb, 0.f));
      }
    __syncthreads();
    s16x8 hf[2][4];
#pragma unroll
    for (int jh=0;jh<2;++jh)
#pragma unroll
      for (int kk=0;kk<4;++kk)
        hf[jh][kk] = *(const s16x8*)&tl[(jh*16 + r)*WPAD + kk*32 + grp*8];
    f32x4 gacc[2][8];
#pragma unroll
    for (int jh=0;jh<2;++jh)
#pragma unroll
      for (int ct=0;ct<8;++ct) gacc[jh][ct] = (f32x4){0.f,0.f,0.f,0.f};
#pragma unroll
    for (int ct=0;ct<8;++ct)
#pragma unroll
      for (int kk=0;kk<4;++kk){
        s16x8 bw = ldB(1,ct,kk);
#pragma unroll
        for (int jh=0;jh<2;++jh)
          gacc[jh][ct] = __builtin_amdgcn_mfma_f32_16x16x32_bf16(hf[jh][kk], bw, gacc[jh][ct], 0,0,0);
      }
    // softmax over the 16 neighbor rows per column + weighted sum of (v+pe)
#pragma unroll
    for (int jh=0;jh<2;++jh){
      int j = pr*2+jh;
#pragma unroll
      for (int ct=0;ct<8;++ct){
        int col = ct*16+r;
        float gb = blds[640+col];
        float g0v = gacc[jh][ct][0]+gb, g1v = gacc[jh][ct][1]+gb;
        float g2v = gacc[jh][ct][2]+gb, g3v = gacc[jh][ct][3]+gb;
        float mx = fmaxf(fmaxf(g0v,g1v), fmaxf(g2v,g3v));
        mx = fmaxf(mx, __shfl_xor(mx,16));
        mx = fmaxf(mx, __shfl_xor(mx,32));
        float e0=__expf(g0v-mx), e1=__expf(g1v-mx), e2=__expf(g2v-mx), e3=__expf(g3v-mx);
        float vb = blds[256+col] + blds[384+col];     // bv + bp2
        float ss = e0+e1+e2+e3;
        float oo = e0*(av[j][ct][0]+vb) + e1*(av[j][ct][1]+vb)
                 + e2*(av[j][ct][2]+vb) + e3*(av[j][ct][3]+vb);
        ss += __shfl_xor(ss,16); ss += __shfl_xor(ss,32);
        oo += __shfl_xor(oo,16); oo += __shfl_xor(oo,32);
        if (grp == 0) out[(size_t)(pbase + w*4 + j)*CDIM + col] = oo/ss;
      }
    }
  }
}

extern "C" void kernel_launch(void* const* d_in, const int* in_sizes, int n_in,
                              void* d_out, int out_size, void* d_ws, size_t ws_size,
                              hipStream_t stream)
{
  const float* x    = (const float*)d_in[0];
  const float* pos  = (const float*)d_in[1];
  const float* Wq   = (const float*)d_in[2];
  const float* bq   = (const float*)d_in[3];
  const float* Wk   = (const float*)d_in[4];
  const float* bk   = (const float*)d_in[5];
  const float* Wv   = (const float*)d_in[6];
  const float* bv   = (const float*)d_in[7];
  const float* Wp1  = (const float*)d_in[8];
  const float* bp1  = (const float*)d_in[9];
  const float* Wp2  = (const float*)d_in[10];
  const float* bp2  = (const float*)d_in[11];
  const float* Wg1  = (const float*)d_in[12];
  const float* bg1  = (const float*)d_in[13];
  const float* Wg2  = (const float*)d_in[14];
  const float* bg2  = (const float*)d_in[15];
  float* out = (float*)d_out;

  char* ws = (char*)d_ws;
  int*            idxs = (int*)ws;                        // 16384*16*4 = 1048576 B
  unsigned short* wt   = (unsigned short*)(ws + 1048576); // 6*17408*2 = 208896 B
  float4*         pos4 = (float4*)(ws + 1257472);         // 16384*16  = 262144 B

  hipFuncSetAttribute((const void*)fused_kernel,
                      hipFuncAttributeMaxDynamicSharedMemorySize, LDS_BYTES);

  prep_kernel<<<472, 256, 0, stream>>>(Wq, Wk, Wv, Wp2, Wg1, Wg2, pos, wt, pos4);
  knn_kernel<<<4096, 256, 0, stream>>>(pos4, idxs);
  fused_kernel<<<1024, 256, LDS_BYTES, stream>>>(x, pos, bq, bk, bv, Wp1, bp1, bp2,
                                                 bg1, bg2, idxs, wt, out);
}

// Round 3
// 314.838 us; speedup vs baseline: 3.1559x; 1.0232x over previous
//
#include <hip/hip_runtime.h>
#include <stdint.h>

#define NPTS 8192
#define CDIM 128
#define KNNK 16
#define WPAD 136
#define WELEM (CDIM*WPAD)          // 17408 elems per transposed weight image
#define SCALE 0.08838834764831845f
#define FLDS_BYTES 78848

typedef __attribute__((ext_vector_type(4))) float f32x4;
typedef __attribute__((ext_vector_type(8))) short s16x8;

__device__ __forceinline__ unsigned short to_bf16(float f){
  union { float f; unsigned int u; } v; v.f = f;
  return (unsigned short)((v.u + 0x7fffu + ((v.u >> 16) & 1u)) >> 16);
}

__device__ __forceinline__ s16x8 cvt8(const float* p){
  float4 lo = *(const float4*)p;
  float4 hi = *(const float4*)(p + 4);
  s16x8 f;
  f[0]=(short)to_bf16(lo.x); f[1]=(short)to_bf16(lo.y);
  f[2]=(short)to_bf16(lo.z); f[3]=(short)to_bf16(lo.w);
  f[4]=(short)to_bf16(hi.x); f[5]=(short)to_bf16(hi.y);
  f[6]=(short)to_bf16(hi.z); f[7]=(short)to_bf16(hi.w);
  return f;
}

// ---------------- prep: transpose weights to bf16 images in ws, pack pos4 ----------------
__global__ __launch_bounds__(256) void prep_kernel(
    const float* __restrict__ Wq, const float* __restrict__ Wk,
    const float* __restrict__ Wv, const float* __restrict__ Wp2,
    const float* __restrict__ Wg1, const float* __restrict__ Wg2,
    const float* __restrict__ pos,
    unsigned short* __restrict__ wt, float4* __restrict__ pos4)
{
  int t = blockIdx.x*256 + threadIdx.x;
  if (t < 6*WELEM){
    int w = t / WELEM, rem = t % WELEM, c = rem / WPAD, i = rem % WPAD;
    const float* src = (w==0)?Wq:(w==1)?Wk:(w==2)?Wv:(w==3)?Wp2:(w==4)?Wg1:Wg2;
    float v = (i < CDIM) ? src[i*CDIM + c] : 0.0f;
    if (w == 1) v = -v;                     // store -Wk so k folds into the t accumulator
    wt[t] = to_bf16(v);
  } else {
    int m = t - 6*WELEM;
    if (m < 2*NPTS){
      float xx = pos[m*3+0], yy = pos[m*3+1], zz = pos[m*3+2];
      float p2 = __fadd_rn(__fadd_rn(__fmul_rn(xx,xx), __fmul_rn(yy,yy)), __fmul_rn(zz,zz));
      pos4[m] = make_float4(xx, yy, zz, p2);
    }
  }
}

// ---------------- kNN: 4 queries/block, LDS-shared candidates, sorted 16-lane list ----------------
__global__ __launch_bounds__(256) void knn_kernel(
    const float4* __restrict__ pos4, int* __restrict__ idxout)
{
  __shared__ float4 cl[1024];                  // 16 KB candidate chunk
  const int tid  = threadIdx.x;
  const int lane = tid & 63;
  const int g = blockIdx.x*4 + (tid >> 6);
  const int b = g >> 13, n = g & (NPTS-1);
  const float4* pb = pos4 + (size_t)b*NPTS;
  const float4 q = pb[n];

  // sorted top-16 list in lanes 0..15 as ordered keys (mapped d, idx); sentinel = max
  unsigned khi = 0xFFFFFFFFu, klo = 0xFFFFFFFFu;
  float Tf = __builtin_inff();                 // wave-uniform threshold (raw float)

  auto mapk = [](float d)->unsigned {
    unsigned s = __float_as_uint(d);
    return s ^ (0x80000000u | (unsigned)(((int)s) >> 31));
  };
  auto insert = [&](unsigned ihi, unsigned ilo){
    unsigned phi = (unsigned)__builtin_amdgcn_update_dpp(0, (int)khi, 0x111, 0xF, 0xF, false);
    unsigned plo = (unsigned)__builtin_amdgcn_update_dpp(0, (int)klo, 0x111, 0xF, 0xF, false);
    bool gt  = (khi > ihi) || (khi == ihi && klo > ilo);
    bool pgt = ((lane & 15) != 0) && ((phi > ihi) || (phi == ihi && plo > ilo));
    khi = gt ? (pgt ? phi : ihi) : khi;
    klo = gt ? (pgt ? plo : ilo) : klo;
  };
  auto updT = [&](){
    unsigned t15 = (unsigned)__builtin_amdgcn_readlane((int)khi, 15);
    unsigned raw = (t15 & 0x80000000u) ? (t15 ^ 0x80000000u) : ~t15;
    Tf = __uint_as_float(raw);
  };
  auto handler = [&](float dv, int gbase, unsigned long long mask){
    while (mask){
      int s = (int)__builtin_ctzll(mask);
      mask &= mask - 1;
      float dsv = __uint_as_float((unsigned)__builtin_amdgcn_readlane((int)__float_as_uint(dv), s));
      insert(mapk(dsv), (unsigned)(gbase + s));
    }
    updT();
  };
  auto body = [&](int loff, int gbase0, unsigned long long excl){
    float d0, d1, d2, d3;
    {
      float4 c = cl[loff + lane];
      float dot = __builtin_fmaf(c.z,q.z, __builtin_fmaf(c.y,q.y, __fmul_rn(c.x,q.x)));
      d0 = __fsub_rn(__fadd_rn(q.w,c.w), __fadd_rn(dot,dot));
    }
    {
      float4 c = cl[loff + 64 + lane];
      float dot = __builtin_fmaf(c.z,q.z, __builtin_fmaf(c.y,q.y, __fmul_rn(c.x,q.x)));
      d1 = __fsub_rn(__fadd_rn(q.w,c.w), __fadd_rn(dot,dot));
    }
    {
      float4 c = cl[loff + 128 + lane];
      float dot = __builtin_fmaf(c.z,q.z, __builtin_fmaf(c.y,q.y, __fmul_rn(c.x,q.x)));
      d2 = __fsub_rn(__fadd_rn(q.w,c.w), __fadd_rn(dot,dot));
    }
    {
      float4 c = cl[loff + 192 + lane];
      float dot = __builtin_fmaf(c.z,q.z, __builtin_fmaf(c.y,q.y, __fmul_rn(c.x,q.x)));
      d3 = __fsub_rn(__fadd_rn(q.w,c.w), __fadd_rn(dot,dot));
    }
    bool i0 = d0 <= Tf, i1 = d1 <= Tf, i2 = d2 <= Tf, i3 = d3 <= Tf;
    if (__ballot(i0|i1|i2|i3)){
      unsigned long long m0 = __ballot(i0) & excl;
      if (m0) handler(d0, gbase0, m0);
      unsigned long long m1 = __ballot(i1);
      if (m1) handler(d1, gbase0+64, m1);
      unsigned long long m2 = __ballot(i2);
      if (m2) handler(d2, gbase0+128, m2);
      unsigned long long m3 = __ballot(i3);
      if (m3) handler(d3, gbase0+192, m3);
    }
  };

  // stage chunk 0
#pragma unroll
  for (int i=0;i<4;++i) cl[tid + i*256] = pb[tid + i*256];
  __syncthreads();

  // warm start: insert candidates 0..15 unconditionally (their d lives in lane m)
  {
    float4 c = cl[lane];
    float dot = __builtin_fmaf(c.z,q.z, __builtin_fmaf(c.y,q.y, __fmul_rn(c.x,q.x)));
    float d0 = __fsub_rn(__fadd_rn(q.w,c.w), __fadd_rn(dot,dot));
    for (int s=0;s<16;++s){
      float dsv = __uint_as_float((unsigned)__builtin_amdgcn_readlane((int)__float_as_uint(d0), s));
      insert(mapk(dsv), (unsigned)s);
    }
    updT();
  }
  body(0, 0, 0xFFFFFFFFFFFF0000ull);           // rest of first 256 (skip 0..15)
  body(256, 256, ~0ull);
  body(512, 512, ~0ull);
  body(768, 768, ~0ull);

  for (int c=1;c<8;++c){
    __syncthreads();
#pragma unroll
    for (int i=0;i<4;++i) cl[tid + i*256] = pb[c*1024 + tid + i*256];
    __syncthreads();
    body(0,   c*1024,       ~0ull);
    body(256, c*1024 + 256, ~0ull);
    body(512, c*1024 + 512, ~0ull);
    body(768, c*1024 + 768, ~0ull);
  }
  if (lane < KNNK) idxout[(size_t)g*KNNK + lane] = (int)klo;
}

// ---------------- fused transform: 4 waves x 2 points, single-slot staging ----------------
__global__ __launch_bounds__(256, 2) void fused_kernel(
    const float* __restrict__ x, const float* __restrict__ pos,
    const float* __restrict__ bq, const float* __restrict__ bk,
    const float* __restrict__ bv, const float* __restrict__ Wp1,
    const float* __restrict__ bp1, const float* __restrict__ bp2,
    const float* __restrict__ bg1, const float* __restrict__ bg2,
    const int* __restrict__ idxws, const unsigned short* __restrict__ wt,
    float* __restrict__ out)
{
  extern __shared__ char smem[];
  unsigned short* WTl = (unsigned short*)smem;               // 1 slot: 34816 B
  float* q_lds = (float*)(smem + 34816);                     // [8][128] f32 = 4096
  unsigned short* t_base = (unsigned short*)(smem + 38912);  // 4 waves x [2][16][136] = 34816
  float* blds = (float*)(smem + 73728);                      // 1280 f32 = 5120

  const int tid = threadIdx.x;
  const int lane = tid & 63, w = tid >> 6;
  const int r = lane & 15, grp = lane >> 4;
  const int pbase = blockIdx.x * 8;
  const int b = pbase >> 13;

  auto stageW = [&](int s){
    const float4* src = (const float4*)(wt + (size_t)s*WELEM);
    float4* dst = (float4*)smem;
    for (int cix = tid; cix < WELEM/8; cix += 256) dst[cix] = src[cix];
  };
  auto ldB = [&](int ct, int kk) -> s16x8 {
    return *(const s16x8*)&WTl[(ct*16 + r)*WPAD + kk*32 + grp*8];
  };

  // stage biases + Wp1 (f32)
  for (int e = tid; e < 1280; e += 256){
    float v;
    if      (e < 128)  v = bq[e];
    else if (e < 256)  v = bk[e-128];
    else if (e < 384)  v = bv[e-256];
    else if (e < 512)  v = bp2[e-384];
    else if (e < 640)  v = bg1[e-512];
    else if (e < 768)  v = bg2[e-640];
    else if (e < 896)  v = bp1[e-768];
    else               v = Wp1[e-896];
    blds[e] = v;
  }
  stageW(0);   // Wq

  // per-lane neighbor info for this wave's 2 points (lane's row r = neighbor slot)
  int nbr[2]; float relx[2], rely[2], relz[2];
#pragma unroll
  for (int j = 0; j < 2; ++j){
    int gp = pbase + w*2 + j;
    nbr[j] = idxws[(size_t)gp*KNNK + r];
    const float* pq = pos + (size_t)gp*3;
    const float* pn = pos + ((size_t)b*NPTS + nbr[j])*3;
    relx[j] = pq[0]-pn[0]; rely[j] = pq[1]-pn[1]; relz[j] = pq[2]-pn[2];
  }
  // A-frags of x rows for the q tile (block's 8 points, rows 8..15 duplicate)
  s16x8 qa[4];
  {
    const float* xr = x + (size_t)(pbase + (r & 7))*CDIM;
#pragma unroll
    for (int kk = 0; kk < 4; ++kk) qa[kk] = cvt8(xr + kk*32 + grp*8);
  }
  __syncthreads();   // Wq + blds visible

  // ---- q = x@Wq + bq: wave w computes column tiles 2w, 2w+1 ----
  {
    f32x4 qacc[2] = { {0.f,0.f,0.f,0.f}, {0.f,0.f,0.f,0.f} };
#pragma unroll
    for (int c2 = 0; c2 < 2; ++c2){
      int ct = w*2 + c2;
#pragma unroll
      for (int kk = 0; kk < 4; ++kk)
        qacc[c2] = __builtin_amdgcn_mfma_f32_16x16x32_bf16(qa[kk], ldB(ct,kk), qacc[c2], 0,0,0);
    }
#pragma unroll
    for (int c2 = 0; c2 < 2; ++c2){
      int col = (w*2+c2)*16 + r;
#pragma unroll
      for (int jj = 0; jj < 4; ++jj){
        int row = grp*4 + jj;
        if (row < 8) q_lds[row*CDIM + col] = qacc[c2][jj] + blds[col];
      }
    }
  }
  // ---- pe1 = relu(rel@Wp1 + bp1) directly in A-frag layout ----
  s16x8 pf[2][4];
#pragma unroll
  for (int j = 0; j < 2; ++j)
#pragma unroll
    for (int kk = 0; kk < 4; ++kk){
      s16x8 f;
#pragma unroll
      for (int i = 0; i < 8; ++i){
        int kc = kk*32 + grp*8 + i;
        float s = relx[j]*blds[896+kc] + rely[j]*blds[1024+kc] + relz[j]*blds[1152+kc] + blds[768+kc];
        f[i] = (short)to_bf16(fmaxf(s, 0.f));
      }
      pf[j][kk] = f;
    }
  __syncthreads();   // Wq consumed, q_lds written
  stageW(3);         // Wp2
  __syncthreads();

  // ---- at = pe1@Wp2 ; av = copy ----
  f32x4 at[2][8], av[2][8];
#pragma unroll
  for (int j=0;j<2;++j)
#pragma unroll
    for (int ct=0;ct<8;++ct) at[j][ct] = (f32x4){0.f,0.f,0.f,0.f};
#pragma unroll
  for (int ct=0;ct<8;++ct)
#pragma unroll
    for (int kk=0;kk<4;++kk){
      s16x8 bw = ldB(ct,kk);
#pragma unroll
      for (int j=0;j<2;++j)
        at[j][ct] = __builtin_amdgcn_mfma_f32_16x16x32_bf16(pf[j][kk], bw, at[j][ct], 0,0,0);
    }
#pragma unroll
  for (int j=0;j<2;++j)
#pragma unroll
    for (int ct=0;ct<8;++ct) av[j][ct] = at[j][ct];
  // prefetch neighbor A-frags (latency hides under -Wk staging)
  s16x8 nf[2][4];
#pragma unroll
  for (int j=0;j<2;++j)
#pragma unroll
    for (int kk=0;kk<4;++kk)
      nf[j][kk] = cvt8(x + ((size_t)b*NPTS + nbr[j])*CDIM + kk*32 + grp*8);

  __syncthreads();   // Wp2 consumed
  stageW(1);         // -Wk
  __syncthreads();
#pragma unroll
  for (int ct=0;ct<8;++ct)
#pragma unroll
    for (int kk=0;kk<4;++kk){
      s16x8 bw = ldB(ct,kk);
#pragma unroll
      for (int j=0;j<2;++j) at[j][ct] = __builtin_amdgcn_mfma_f32_16x16x32_bf16(nf[j][kk], bw, at[j][ct], 0,0,0);
    }
  __syncthreads();   // -Wk consumed
  stageW(2);         // Wv
  __syncthreads();
#pragma unroll
  for (int ct=0;ct<8;++ct)
#pragma unroll
    for (int kk=0;kk<4;++kk){
      s16x8 bw = ldB(ct,kk);
#pragma unroll
      for (int j=0;j<2;++j) av[j][ct] = __builtin_amdgcn_mfma_f32_16x16x32_bf16(nf[j][kk], bw, av[j][ct], 0,0,0);
    }
  // t = (q - k + pe) * scale
#pragma unroll
  for (int j=0;j<2;++j){
    int prow = (w*2+j)*CDIM;
#pragma unroll
    for (int ct=0;ct<8;++ct){
      int col = ct*16+r;
      float add = q_lds[prow+col] + blds[384+col] - blds[128+col];
#pragma unroll
      for (int jj=0;jj<4;++jj) at[j][ct][jj] = (at[j][ct][jj] + add)*SCALE;
    }
  }
  __syncthreads();   // Wv consumed
  stageW(4);         // Wg1
  __syncthreads();

  // ---- gating MLP (both points at once; tl region is per-wave) ----
  unsigned short* tl = t_base + w*(2*16*WPAD);
#pragma unroll
  for (int j=0;j<2;++j)
#pragma unroll
    for (int ct=0;ct<8;++ct)
#pragma unroll
      for (int jj=0;jj<4;++jj)
        tl[(j*16 + grp*4+jj)*WPAD + ct*16 + r] = to_bf16(at[j][ct][jj]);
  s16x8 tf[2][4];
#pragma unroll
  for (int j=0;j<2;++j)
#pragma unroll
    for (int kk=0;kk<4;++kk)
      tf[j][kk] = *(const s16x8*)&tl[(j*16 + r)*WPAD + kk*32 + grp*8];
  f32x4 hacc[2][8];
#pragma unroll
  for (int j=0;j<2;++j)
#pragma unroll
    for (int ct=0;ct<8;++ct) hacc[j][ct] = (f32x4){0.f,0.f,0.f,0.f};
#pragma unroll
  for (int ct=0;ct<8;++ct)
#pragma unroll
    for (int kk=0;kk<4;++kk){
      s16x8 bw = ldB(ct,kk);
#pragma unroll
      for (int j=0;j<2;++j)
        hacc[j][ct] = __builtin_amdgcn_mfma_f32_16x16x32_bf16(tf[j][kk], bw, hacc[j][ct], 0,0,0);
    }
  __syncthreads();   // Wg1 consumed
  stageW(5);         // Wg2
  __syncthreads();
#pragma unroll
  for (int j=0;j<2;++j)
#pragma unroll
    for (int ct=0;ct<8;++ct){
      int col = ct*16+r; float bb = blds[512+col];
#pragma unroll
      for (int jj=0;jj<4;++jj)
        tl[(j*16+grp*4+jj)*WPAD + ct*16 + r] = to_bf16(fmaxf(hacc[j][ct][jj]+bb, 0.f));
    }
  s16x8 hf[2][4];
#pragma unroll
  for (int j=0;j<2;++j)
#pragma unroll
    for (int kk=0;kk<4;++kk)
      hf[j][kk] = *(const s16x8*)&tl[(j*16 + r)*WPAD + kk*32 + grp*8];
  f32x4 gacc[2][8];
#pragma unroll
  for (int j=0;j<2;++j)
#pragma unroll
    for (int ct=0;ct<8;++ct) gacc[j][ct] = (f32x4){0.f,0.f,0.f,0.f};
#pragma unroll
  for (int ct=0;ct<8;++ct)
#pragma unroll
    for (int kk=0;kk<4;++kk){
      s16x8 bw = ldB(ct,kk);
#pragma unroll
      for (int j=0;j<2;++j)
        gacc[j][ct] = __builtin_amdgcn_mfma_f32_16x16x32_bf16(hf[j][kk], bw, gacc[j][ct], 0,0,0);
    }
  // ---- softmax over 16 neighbors + weighted sum of (v+pe) ----
#pragma unroll
  for (int j=0;j<2;++j){
#pragma unroll
    for (int ct=0;ct<8;++ct){
      int col = ct*16+r;
      float gb = blds[640+col];
      float g0v = gacc[j][ct][0]+gb, g1v = gacc[j][ct][1]+gb;
      float g2v = gacc[j][ct][2]+gb, g3v = gacc[j][ct][3]+gb;
      float mx = fmaxf(fmaxf(g0v,g1v), fmaxf(g2v,g3v));
      mx = fmaxf(mx, __shfl_xor(mx,16));
      mx = fmaxf(mx, __shfl_xor(mx,32));
      float e0=__expf(g0v-mx), e1=__expf(g1v-mx), e2=__expf(g2v-mx), e3=__expf(g3v-mx);
      float vb = blds[256+col] + blds[384+col];     // bv + bp2
      float ss = e0+e1+e2+e3;
      float oo = e0*(av[j][ct][0]+vb) + e1*(av[j][ct][1]+vb)
               + e2*(av[j][ct][2]+vb) + e3*(av[j][ct][3]+vb);
      ss += __shfl_xor(ss,16); ss += __shfl_xor(ss,32);
      oo += __shfl_xor(oo,16); oo += __shfl_xor(oo,32);
      if (grp == 0) out[(size_t)(pbase + w*2 + j)*CDIM + col] = oo/ss;
    }
  }
}

extern "C" void kernel_launch(void* const* d_in, const int* in_sizes, int n_in,
                              void* d_out, int out_size, void* d_ws, size_t ws_size,
                              hipStream_t stream)
{
  const float* x    = (const float*)d_in[0];
  const float* pos  = (const float*)d_in[1];
  const float* Wq   = (const float*)d_in[2];
  const float* bq   = (const float*)d_in[3];
  const float* Wk   = (const float*)d_in[4];
  const float* bk   = (const float*)d_in[5];
  const float* Wv   = (const float*)d_in[6];
  const float* bv   = (const float*)d_in[7];
  const float* Wp1  = (const float*)d_in[8];
  const float* bp1  = (const float*)d_in[9];
  const float* Wp2  = (const float*)d_in[10];
  const float* bp2  = (const float*)d_in[11];
  const float* Wg1  = (const float*)d_in[12];
  const float* bg1  = (const float*)d_in[13];
  const float* Wg2  = (const float*)d_in[14];
  const float* bg2  = (const float*)d_in[15];
  float* out = (float*)d_out;

  char* ws = (char*)d_ws;
  int*            idxs = (int*)ws;                        // 16384*16*4 = 1048576 B
  unsigned short* wt   = (unsigned short*)(ws + 1048576); // 6*17408*2 = 208896 B
  float4*         pos4 = (float4*)(ws + 1257472);         // 16384*16  = 262144 B

  hipFuncSetAttribute((const void*)fused_kernel,
                      hipFuncAttributeMaxDynamicSharedMemorySize, FLDS_BYTES);

  prep_kernel<<<472, 256, 0, stream>>>(Wq, Wk, Wv, Wp2, Wg1, Wg2, pos, wt, pos4);
  knn_kernel<<<4096, 256, 0, stream>>>(pos4, idxs);
  fused_kernel<<<2048, 256, FLDS_BYTES, stream>>>(x, pos, bq, bk, bv, Wp1, bp1, bp2,
                                                  bg1, bg2, idxs, wt, out);
}